// Round 11
// baseline (210.083 us; speedup 1.0000x reference)
//
#include <hip/hip_runtime.h>

typedef __attribute__((ext_vector_type(8))) short short8;
typedef __attribute__((ext_vector_type(4))) float f32x4;
typedef __attribute__((ext_vector_type(4))) short short4v;
typedef __attribute__((ext_vector_type(4))) unsigned short ushort4v;

#define DEV static __device__ __forceinline__

// fp32 -> bf16 round-to-nearest-even
DEV unsigned short f2bf(float f) {
  unsigned int u = __builtin_bit_cast(unsigned int, f);
  u += 0x7fffu + ((u >> 16) & 1u);
  return (unsigned short)(u >> 16);
}

DEV unsigned int pack2bf(float a, float b) {
  return (unsigned int)f2bf(a) | ((unsigned int)f2bf(b) << 16);
}

DEV void gload16(const void* g, void* l) {
  __builtin_amdgcn_global_load_lds(
      (const __attribute__((address_space(1))) unsigned int*)g,
      (__attribute__((address_space(3))) unsigned int*)l, 16, 0, 0);
}

// ---------------- convert f32 -> bf16 (vec4) ----------------
__global__ __launch_bounds__(256) void cvt_bf16(const float* __restrict__ in,
                                                unsigned short* __restrict__ out,
                                                int nvec4) {
  int i = blockIdx.x * 256 + threadIdx.x;
  if (i >= nvec4) return;
  float4 v = ((const float4*)in)[i];
  ushort4v o = {f2bf(v.x), f2bf(v.y), f2bf(v.z), f2bf(v.w)};
  *(ushort4v*)(out + (size_t)i * 4) = o;
}

// all four 768x768 weights in one dispatch (dest buffers are contiguous in ws)
__global__ __launch_bounds__(256) void cvt_w4(const float* __restrict__ w0,
                                              const float* __restrict__ w1,
                                              const float* __restrict__ w2,
                                              const float* __restrict__ w3,
                                              unsigned short* __restrict__ out) {
  int i = blockIdx.x * 256 + threadIdx.x;  // 2304 blocks * 256 = 589824 exactly
  int wsel = i / 147456;
  int j = i - wsel * 147456;
  const float* src = wsel == 0 ? w0 : wsel == 1 ? w1 : wsel == 2 ? w2 : w3;
  float4 v = ((const float4*)src)[j];
  ushort4v o = {f2bf(v.x), f2bf(v.y), f2bf(v.z), f2bf(v.w)};
  *(ushort4v*)(out + (size_t)i * 4) = o;
}

// ---------------- fused QKV GEMM (2-phase prefetch, dbuf LDS) ----------------
__global__ __launch_bounds__(256) void gemm_qkv(const short* __restrict__ A,
                                                const short* __restrict__ B0,
                                                unsigned short* __restrict__ QK,
                                                unsigned short* __restrict__ Vt) {
  __shared__ short As[2][128 * 32];
  __shared__ short Bs[2][128 * 32];
  const int tid = threadIdx.x;
  const int lane = tid & 63;
  const int wave = tid >> 6;
  const int row0 = blockIdx.x * 128;
  const int wsel = blockIdx.y / 6;
  const int col0 = (blockIdx.y % 6) * 128;
  const short* B = B0 + (size_t)wsel * 589824;
  const int wr = (wave >> 1) * 64;
  const int wc = (wave & 1) * 64;

  f32x4 acc[4][4] = {};

  const short* aG = A + (size_t)(row0 + wave * 16 + (lane >> 2)) * 768 + (lane & 3) * 8;
  const short* bG = B + (size_t)(col0 + wave * 16 + (lane >> 2)) * 768 + (lane & 3) * 8;
  char* aL = (char*)&As[0][0] + wave * 1024;  // wave-uniform LDS base (+lane*16 by HW)
  char* bL = (char*)&Bs[0][0] + wave * 1024;

  const int cl = lane & 15;
  const int g8 = (lane >> 4) * 8;

#define QKV_STAGE(buf, kk)                          \
  do {                                              \
    gload16(aG + (kk), aL + (buf)*8192);            \
    gload16(aG + 64 * 768 + (kk), aL + (buf)*8192 + 4096); \
    gload16(bG + (kk), bL + (buf)*8192);            \
    gload16(bG + 64 * 768 + (kk), bL + (buf)*8192 + 4096); \
  } while (0)

#define QKV_COMPUTE(buf)                                                          \
  do {                                                                            \
    short8 af[4], bfr[4];                                                         \
    _Pragma("unroll") for (int m = 0; m < 4; m++)                                 \
        af[m] = *(const short8*)&As[buf][(wr + m * 16 + cl) * 32 + g8];           \
    _Pragma("unroll") for (int n = 0; n < 4; n++)                                 \
        bfr[n] = *(const short8*)&Bs[buf][(wc + n * 16 + cl) * 32 + g8];          \
    _Pragma("unroll") for (int m = 0; m < 4; m++)                                 \
        _Pragma("unroll") for (int n = 0; n < 4; n++)                             \
            acc[m][n] = __builtin_amdgcn_mfma_f32_16x16x32_bf16(af[m], bfr[n],    \
                                                                acc[m][n], 0, 0, 0); \
  } while (0)

  QKV_STAGE(0, 0);
  __syncthreads();
  int cur = 0;
  for (int kk = 32; kk < 768; kk += 32) {
    QKV_STAGE(cur ^ 1, kk);   // prefetch next tile (in flight across compute)
    QKV_COMPUTE(cur);
    __syncthreads();          // drains vmcnt after compute; one barrier per K-step
    cur ^= 1;
  }
  QKV_COMPUTE(cur);

  const int r4 = (lane >> 4) * 4;
  unsigned short* Qout = QK + (size_t)wsel * 6291456;
#pragma unroll
  for (int m = 0; m < 4; m++) {
#pragma unroll
    for (int n = 0; n < 4; n++) {
      const int row = row0 + wr + m * 16 + r4;
      const int col = col0 + wc + n * 16 + cl;
      if (wsel < 2) {
#pragma unroll
        for (int r = 0; r < 4; r++) {
          Qout[(size_t)(((((row + r) >> 10) * 12 + (col >> 6)) << 16) +
                        (((row + r) & 1023) << 6) + (col & 63))] = f2bf(acc[m][n][r]);
        }
      } else {
        // V^T: lane's 4 regs are 4 consecutive rows = contiguous -> one 8B store
        short4v ov;
#pragma unroll
        for (int r = 0; r < 4; r++) ov[r] = (short)f2bf(acc[m][n][r]);
        *(short4v*)((short*)Vt + (size_t)((((row >> 10) * 12 + (col >> 6)) << 16) +
                                          ((col & 63) << 10) + (row & 1023))) = ov;
      }
    }
  }
}

// ---------------- output GEMM (2-phase prefetch, dbuf LDS) ----------------
__global__ __launch_bounds__(256) void gemm_out(const short* __restrict__ A,
                                                const short* __restrict__ B,
                                                float* __restrict__ Cout,
                                                const float* __restrict__ bias) {
  __shared__ short As[2][128 * 32];
  __shared__ short Bs[2][128 * 32];
  const int tid = threadIdx.x;
  const int lane = tid & 63;
  const int wave = tid >> 6;
  const int row0 = blockIdx.x * 128;
  const int col0 = blockIdx.y * 128;
  const int wr = (wave >> 1) * 64;
  const int wc = (wave & 1) * 64;

  f32x4 acc[4][4] = {};

  const short* aG = A + (size_t)(row0 + wave * 16 + (lane >> 2)) * 768 + (lane & 3) * 8;
  const short* bG = B + (size_t)(col0 + wave * 16 + (lane >> 2)) * 768 + (lane & 3) * 8;
  char* aL = (char*)&As[0][0] + wave * 1024;
  char* bL = (char*)&Bs[0][0] + wave * 1024;

  const int cl = lane & 15;
  const int g8 = (lane >> 4) * 8;

  QKV_STAGE(0, 0);
  __syncthreads();
  int cur = 0;
  for (int kk = 32; kk < 768; kk += 32) {
    QKV_STAGE(cur ^ 1, kk);
    QKV_COMPUTE(cur);
    __syncthreads();
    cur ^= 1;
  }
  QKV_COMPUTE(cur);

  const int r4 = (lane >> 4) * 4;
#pragma unroll
  for (int m = 0; m < 4; m++) {
#pragma unroll
    for (int n = 0; n < 4; n++) {
#pragma unroll
      for (int r = 0; r < 4; r++) {
        const int row = row0 + wr + m * 16 + r4 + r;
        const int col = col0 + wc + n * 16 + cl;
        Cout[(size_t)row * 768 + col] = acc[m][n][r] + bias[col];
      }
    }
  }
}

// ---------------- causal flash attention, split-K, 8 waves ----------------
// Qh,Kh: [nh][1024][64] bf16.  Vt: [nh][64][1024] bf16.  Obuf: [8192][768] bf16.
// grid (8, 96) x 512 threads. Two 4-wave groups split each q-tile's KV range
// in half (uniform 17 tile-steps/group); phase-end (m,l,o) merge via LDS.
// Phases: q-tile bx, then 15-bx (balanced causal pair).
__global__ __launch_bounds__(512) void attn_fwd(const short* __restrict__ Qh,
                                                const short* __restrict__ Kh,
                                                const short* __restrict__ Vt,
                                                short* __restrict__ Obuf) {
  __shared__ short Ks[2][32 * 72];          // per group: 32 x 64, padded +8
  __shared__ short Vs[2][64 * 40];          // per group: 64 x 32, padded +8
  __shared__ unsigned int Ps[8][16 * 36];   // per-wave P exchange; aliased merge buf

  const int tid = threadIdx.x;
  const int lane = tid & 63;
  const int wave = tid >> 6;
  const int w4 = wave & 3;
  const int gg = wave >> 2;                 // KV-split group 0/1
  const int t8 = tid & 255;
  const int nh = blockIdx.y;
  const int nIdx = nh / 12;
  const int hIdx = nh % 12;
  const int hb = nh << 16;                  // nh * 1024 * 64
  const int qloc = lane & 15;
  const int g = lane >> 4;
  const int kRow = t8 >> 3, kColB = (t8 & 7) * 8;
  const int vRow = t8 >> 2, vColB = (t8 & 3) * 8;
  short* KsG = &Ks[gg][0];
  short* VsG = &Vs[gg][0];
  float* Mbuf = (float*)&Ps[0][0];          // 4608 floats = 256 lanes x 18
  float* slot = Mbuf + (size_t)(w4 * 64 + lane) * 18;

  const float SCL = 0.18033688f;            // 0.125 * log2(e): exp2-domain softmax

  for (int p = 0; p < 2; p++) {
    const int qb = p ? (15 - (int)blockIdx.x) : (int)blockIdx.x;
    const int nsteps = qb + 1;              // KV-tiles per group (32 rows each)
    const int qr0 = qb * 64 + w4 * 16;
    const int qg = qr0 + qloc;
    const int qmax = qr0 + 15;

    short8 qf[2];
    qf[0] = *(const short8*)&Qh[hb + qg * 64 + g * 8];
    qf[1] = *(const short8*)&Qh[hb + qg * 64 + 32 + g * 8];

    float m_run = -INFINITY, l_run = 0.f;
    f32x4 o[4] = {};

    for (int s = 0; s < nsteps; s++) {
      const int kv0 = (s + gg * nsteps) * 32;
      *(short8*)&KsG[kRow * 72 + kColB] = *(const short8*)&Kh[hb + (kv0 + kRow) * 64 + kColB];
      *(short8*)&VsG[vRow * 40 + vColB] = *(const short8*)&Vt[hb + vRow * 1024 + kv0 + vColB];
      __syncthreads();
      if (kv0 <= qmax) {  // wave-uniform: skip fully-masked tiles
        f32x4 s2[2] = {};
#pragma unroll
        for (int c = 0; c < 2; c++) {
          short8 a0 = *(const short8*)&KsG[qloc * 72 + c * 32 + g * 8];
          short8 a1 = *(const short8*)&KsG[(16 + qloc) * 72 + c * 32 + g * 8];
          s2[0] = __builtin_amdgcn_mfma_f32_16x16x32_bf16(a0, qf[c], s2[0], 0, 0, 0);
          s2[1] = __builtin_amdgcn_mfma_f32_16x16x32_bf16(a1, qf[c], s2[1], 0, 0, 0);
        }
        // lane holds S[q=qg][k = kv0 + kt*16 + g*4 + r] (exp2-domain after SCL)
        float pv[2][4];
        float pm = -INFINITY;
        if (kv0 + 31 <= qr0) {  // wave-uniform fast path: tile fully below diagonal
#pragma unroll
          for (int kt = 0; kt < 2; kt++)
#pragma unroll
            for (int r = 0; r < 4; r++) {
              float sv = s2[kt][r] * SCL;
              pv[kt][r] = sv;
              pm = fmaxf(pm, sv);
            }
        } else {
#pragma unroll
          for (int kt = 0; kt < 2; kt++)
#pragma unroll
            for (int r = 0; r < 4; r++) {
              const int kg = kv0 + kt * 16 + g * 4 + r;
              float sv = s2[kt][r] * SCL;
              sv = (kg <= qg) ? sv : -INFINITY;
              pv[kt][r] = sv;
              pm = fmaxf(pm, sv);
            }
        }
        pm = fmaxf(pm, __shfl_xor(pm, 16));
        pm = fmaxf(pm, __shfl_xor(pm, 32));
        if (__all(pm <= m_run + 11.5f)) {
          // defer-max: keep m_run, skip corr-exp and o-rescale (P <= 2^11.5)
          float lsum = 0.f;
#pragma unroll
          for (int kt = 0; kt < 2; kt++)
#pragma unroll
            for (int r = 0; r < 4; r++) {
              float pp = exp2f(pv[kt][r] - m_run);
              pv[kt][r] = pp;
              lsum += pp;
            }
          lsum += __shfl_xor(lsum, 16);
          lsum += __shfl_xor(lsum, 32);
          l_run += lsum;
        } else {
          const float mnew = fmaxf(m_run, pm);
          const float corr = exp2f(m_run - mnew);
          float lsum = 0.f;
#pragma unroll
          for (int kt = 0; kt < 2; kt++)
#pragma unroll
            for (int r = 0; r < 4; r++) {
              float pp = exp2f(pv[kt][r] - mnew);
              pv[kt][r] = pp;
              lsum += pp;
            }
          lsum += __shfl_xor(lsum, 16);
          lsum += __shfl_xor(lsum, 32);
          l_run = l_run * corr + lsum;
          m_run = mnew;
#pragma unroll
          for (int dt = 0; dt < 4; dt++) o[dt] *= corr;
        }
        // repack P (bf16) through per-wave LDS into MFMA B-operand layout
        unsigned int* pr = &Ps[wave][qloc * 36];
#pragma unroll
        for (int kt = 0; kt < 2; kt++) {
          pr[kt * 8 + g * 2] = pack2bf(pv[kt][0], pv[kt][1]);
          pr[kt * 8 + g * 2 + 1] = pack2bf(pv[kt][2], pv[kt][3]);
        }
        __asm__ volatile("" ::: "memory");
        short8 pf = *(const short8*)((const short*)&Ps[wave][0] + qloc * 72 + g * 8);
#pragma unroll
        for (int dt = 0; dt < 4; dt++) {
          short8 vf = *(const short8*)&VsG[(dt * 16 + qloc) * 40 + g * 8];
          o[dt] = __builtin_amdgcn_mfma_f32_16x16x32_bf16(vf, pf, o[dt], 0, 0, 0);
        }
      }
      __syncthreads();
    }

    // ---- merge the two groups' partials (group 1 -> LDS, group 0 combines) ----
    if (gg == 1) {
#pragma unroll
      for (int dt = 0; dt < 4; dt++)
#pragma unroll
        for (int r = 0; r < 4; r++) slot[dt * 4 + r] = o[dt][r];
      slot[16] = m_run;
      slot[17] = l_run;
    }
    __syncthreads();
    if (gg == 0) {
      const float m1 = slot[16], l1 = slot[17];
      const float mm = fmaxf(m_run, m1);
      const float c0 = exp2f(m_run - mm);
      const float c1 = exp2f(m1 - mm);  // m1=-inf (no tiles) -> c1=0
      const float inv = 1.f / (l_run * c0 + l1 * c1);
      const int outRow = nIdx * 1024 + qr0 + qloc;
      short* op = Obuf + (size_t)outRow * 768 + hIdx * 64;
#pragma unroll
      for (int dt = 0; dt < 4; dt++) {
        short4v ov;
#pragma unroll
        for (int r = 0; r < 4; r++)
          ov[r] = (short)f2bf((o[dt][r] * c0 + slot[dt * 4 + r] * c1) * inv);
        *(short4v*)(op + dt * 16 + g * 4) = ov;
      }
    }
    __syncthreads();  // protect merge buf until reads done (next phase reuses Ps)
  }
}

// ---------------- launch ----------------
extern "C" void kernel_launch(void* const* d_in, const int* in_sizes, int n_in,
                              void* d_out, int out_size, void* d_ws, size_t ws_size,
                              hipStream_t stream) {
  (void)in_sizes; (void)n_in; (void)out_size; (void)ws_size;
  const float* x  = (const float*)d_in[0];
  const float* Wq = (const float*)d_in[1];
  const float* Wk = (const float*)d_in[2];
  const float* Wv = (const float*)d_in[3];
  const float* Wo = (const float*)d_in[4];
  const float* bo = (const float*)d_in[5];

  char* ws = (char*)d_ws;
  short* xb  = (short*)(ws);                              // 8192x768 bf16
  short* wqb = (short*)(ws + 12582912);                   // wq,wk,wv,wo contiguous
  short* wob = (short*)(ws + 12582912 + 3 * 1179648);
  short* Qh  = (short*)(ws + 17301504);                   // [96][1024][64] bf16
  short* Kh  = (short*)(ws + 17301504 + 12582912);
  short* Vt  = (short*)(ws + 17301504 + 2 * 12582912);    // [96][64][1024] bf16
  short* Ob  = (short*)(ws + 17301504 + 3 * 12582912);    // [8192][768] bf16

  cvt_bf16<<<6144, 256, 0, stream>>>(x, (unsigned short*)xb, 1572864);
  cvt_w4<<<2304, 256, 0, stream>>>(Wq, Wk, Wv, Wo, (unsigned short*)wqb);

  gemm_qkv<<<dim3(64, 18), 256, 0, stream>>>(xb, wqb, (unsigned short*)Qh,
                                             (unsigned short*)Vt);

  attn_fwd<<<dim3(8, 96), 512, 0, stream>>>(Qh, Kh, Vt, Ob);

  gemm_out<<<dim3(64, 6), 256, 0, stream>>>(Ob, wob, (float*)d_out, bo);
}

// Round 15
// 201.530 us; speedup vs baseline: 1.0424x; 1.0424x over previous
//
#include <hip/hip_runtime.h>

typedef __attribute__((ext_vector_type(8))) short short8;
typedef __attribute__((ext_vector_type(4))) float f32x4;
typedef __attribute__((ext_vector_type(4))) short short4v;
typedef __attribute__((ext_vector_type(4))) unsigned short ushort4v;

#define DEV static __device__ __forceinline__

// fp32 -> bf16 round-to-nearest-even
DEV unsigned short f2bf(float f) {
  unsigned int u = __builtin_bit_cast(unsigned int, f);
  u += 0x7fffu + ((u >> 16) & 1u);
  return (unsigned short)(u >> 16);
}

DEV unsigned int pack2bf(float a, float b) {
  return (unsigned int)f2bf(a) | ((unsigned int)f2bf(b) << 16);
}

DEV void gload16(const void* g, void* l) {
  __builtin_amdgcn_global_load_lds(
      (const __attribute__((address_space(1))) unsigned int*)g,
      (__attribute__((address_space(3))) unsigned int*)l, 16, 0, 0);
}

// ---------------- convert f32 -> bf16 (vec4) ----------------
__global__ __launch_bounds__(256) void cvt_bf16(const float* __restrict__ in,
                                                unsigned short* __restrict__ out,
                                                int nvec4) {
  int i = blockIdx.x * 256 + threadIdx.x;
  if (i >= nvec4) return;
  float4 v = ((const float4*)in)[i];
  ushort4v o = {f2bf(v.x), f2bf(v.y), f2bf(v.z), f2bf(v.w)};
  *(ushort4v*)(out + (size_t)i * 4) = o;
}

// all four 768x768 weights in one dispatch (dest buffers are contiguous in ws)
__global__ __launch_bounds__(256) void cvt_w4(const float* __restrict__ w0,
                                              const float* __restrict__ w1,
                                              const float* __restrict__ w2,
                                              const float* __restrict__ w3,
                                              unsigned short* __restrict__ out) {
  int i = blockIdx.x * 256 + threadIdx.x;  // 2304 blocks * 256 = 589824 exactly
  int wsel = i / 147456;
  int j = i - wsel * 147456;
  const float* src = wsel == 0 ? w0 : wsel == 1 ? w1 : wsel == 2 ? w2 : w3;
  float4 v = ((const float4*)src)[j];
  ushort4v o = {f2bf(v.x), f2bf(v.y), f2bf(v.z), f2bf(v.w)};
  *(ushort4v*)(out + (size_t)i * 4) = o;
}

// ---------------- fused QKV GEMM (2-phase prefetch, dbuf LDS) ----------------
__global__ __launch_bounds__(256) void gemm_qkv(const short* __restrict__ A,
                                                const short* __restrict__ B0,
                                                unsigned short* __restrict__ QK,
                                                unsigned short* __restrict__ Vt) {
  __shared__ short As[2][128 * 32];
  __shared__ short Bs[2][128 * 32];
  const int tid = threadIdx.x;
  const int lane = tid & 63;
  const int wave = tid >> 6;
  const int row0 = blockIdx.x * 128;
  const int wsel = blockIdx.y / 6;
  const int col0 = (blockIdx.y % 6) * 128;
  const short* B = B0 + (size_t)wsel * 589824;
  const int wr = (wave >> 1) * 64;
  const int wc = (wave & 1) * 64;

  f32x4 acc[4][4] = {};

  const short* aG = A + (size_t)(row0 + wave * 16 + (lane >> 2)) * 768 + (lane & 3) * 8;
  const short* bG = B + (size_t)(col0 + wave * 16 + (lane >> 2)) * 768 + (lane & 3) * 8;
  char* aL = (char*)&As[0][0] + wave * 1024;  // wave-uniform LDS base (+lane*16 by HW)
  char* bL = (char*)&Bs[0][0] + wave * 1024;

  const int cl = lane & 15;
  const int g8 = (lane >> 4) * 8;

#define QKV_STAGE(buf, kk)                          \
  do {                                              \
    gload16(aG + (kk), aL + (buf)*8192);            \
    gload16(aG + 64 * 768 + (kk), aL + (buf)*8192 + 4096); \
    gload16(bG + (kk), bL + (buf)*8192);            \
    gload16(bG + 64 * 768 + (kk), bL + (buf)*8192 + 4096); \
  } while (0)

#define QKV_COMPUTE(buf)                                                          \
  do {                                                                            \
    short8 af[4], bfr[4];                                                         \
    _Pragma("unroll") for (int m = 0; m < 4; m++)                                 \
        af[m] = *(const short8*)&As[buf][(wr + m * 16 + cl) * 32 + g8];           \
    _Pragma("unroll") for (int n = 0; n < 4; n++)                                 \
        bfr[n] = *(const short8*)&Bs[buf][(wc + n * 16 + cl) * 32 + g8];          \
    _Pragma("unroll") for (int m = 0; m < 4; m++)                                 \
        _Pragma("unroll") for (int n = 0; n < 4; n++)                             \
            acc[m][n] = __builtin_amdgcn_mfma_f32_16x16x32_bf16(af[m], bfr[n],    \
                                                                acc[m][n], 0, 0, 0); \
  } while (0)

  QKV_STAGE(0, 0);
  __syncthreads();
  int cur = 0;
  for (int kk = 32; kk < 768; kk += 32) {
    QKV_STAGE(cur ^ 1, kk);   // prefetch next tile (in flight across compute)
    QKV_COMPUTE(cur);
    __syncthreads();          // drains vmcnt after compute; one barrier per K-step
    cur ^= 1;
  }
  QKV_COMPUTE(cur);

  const int r4 = (lane >> 4) * 4;
  unsigned short* Qout = QK + (size_t)wsel * 6291456;
#pragma unroll
  for (int m = 0; m < 4; m++) {
#pragma unroll
    for (int n = 0; n < 4; n++) {
      const int row = row0 + wr + m * 16 + r4;
      const int col = col0 + wc + n * 16 + cl;
      if (wsel < 2) {
#pragma unroll
        for (int r = 0; r < 4; r++) {
          Qout[(size_t)(((((row + r) >> 10) * 12 + (col >> 6)) << 16) +
                        (((row + r) & 1023) << 6) + (col & 63))] = f2bf(acc[m][n][r]);
        }
      } else {
        // V^T: lane's 4 regs are 4 consecutive rows = contiguous -> one 8B store
        short4v ov;
#pragma unroll
        for (int r = 0; r < 4; r++) ov[r] = (short)f2bf(acc[m][n][r]);
        *(short4v*)((short*)Vt + (size_t)((((row >> 10) * 12 + (col >> 6)) << 16) +
                                          ((col & 63) << 10) + (row & 1023))) = ov;
      }
    }
  }
}

// ---------------- output GEMM (2-phase prefetch, dbuf LDS) ----------------
__global__ __launch_bounds__(256) void gemm_out(const short* __restrict__ A,
                                                const short* __restrict__ B,
                                                float* __restrict__ Cout,
                                                const float* __restrict__ bias) {
  __shared__ short As[2][128 * 32];
  __shared__ short Bs[2][128 * 32];
  const int tid = threadIdx.x;
  const int lane = tid & 63;
  const int wave = tid >> 6;
  const int row0 = blockIdx.x * 128;
  const int col0 = blockIdx.y * 128;
  const int wr = (wave >> 1) * 64;
  const int wc = (wave & 1) * 64;

  f32x4 acc[4][4] = {};

  const short* aG = A + (size_t)(row0 + wave * 16 + (lane >> 2)) * 768 + (lane & 3) * 8;
  const short* bG = B + (size_t)(col0 + wave * 16 + (lane >> 2)) * 768 + (lane & 3) * 8;
  char* aL = (char*)&As[0][0] + wave * 1024;
  char* bL = (char*)&Bs[0][0] + wave * 1024;

  const int cl = lane & 15;
  const int g8 = (lane >> 4) * 8;

  QKV_STAGE(0, 0);
  __syncthreads();
  int cur = 0;
  for (int kk = 32; kk < 768; kk += 32) {
    QKV_STAGE(cur ^ 1, kk);
    QKV_COMPUTE(cur);
    __syncthreads();
    cur ^= 1;
  }
  QKV_COMPUTE(cur);

  const int r4 = (lane >> 4) * 4;
#pragma unroll
  for (int m = 0; m < 4; m++) {
#pragma unroll
    for (int n = 0; n < 4; n++) {
#pragma unroll
      for (int r = 0; r < 4; r++) {
        const int row = row0 + wr + m * 16 + r4 + r;
        const int col = col0 + wc + n * 16 + cl;
        Cout[(size_t)row * 768 + col] = acc[m][n][r] + bias[col];
      }
    }
  }
}

// ---------------- causal flash attention (4 waves, T14 prefetch, XCD-clustered) --
// Qh,Kh: [nh][1024][64] bf16.  Vt: [nh][64][1024] bf16.  Obuf: [8192][768] bf16.
// 1-D grid 768: bid -> (nh, pair) such that all 8 blocks of a head share one XCD
// (bid%8 selects XCD slot; 12 heads per XCD; K/V then L2-resident ~4.5MB/XCD).
// Block: 4 waves x 16 q-rows; q-tiles (pair, 15-pair) = 34 uniform KV steps.
// K/V staging: reg preload -> LDS write -> barrier -> issue next loads -> compute.
__global__ __launch_bounds__(256) void attn_fwd(const short* __restrict__ Qh,
                                                const short* __restrict__ Kh,
                                                const short* __restrict__ Vt,
                                                short* __restrict__ Obuf) {
  __shared__ short Ks[2][32 * 72];          // 32 x 64, padded +8 (bank spread)
  __shared__ short Vs[2][64 * 40];          // 64 x 32, padded +8
  __shared__ unsigned int Ps[4][16 * 36];   // per-wave P exchange

  const int tid = threadIdx.x;
  const int lane = tid & 63;
  const int w = tid >> 6;
  const int bid = blockIdx.x;
  const int nh = (bid & 7) * 12 + ((bid >> 3) % 12);  // head -> fixed XCD slot
  const int pr = (bid >> 3) / 12;                     // pair index 0..7
  const int nIdx = nh / 12;
  const int hIdx = nh % 12;
  const int hb = nh << 16;                  // nh * 1024 * 64
  const int qloc = lane & 15;
  const int g = lane >> 4;
  const int kRow = tid >> 3, kColB = (tid & 7) * 8;
  const int vRow = tid >> 2, vColB = (tid & 3) * 8;

  const float SCL = 0.18033688f;            // 0.125 * log2(e): exp2-domain softmax

  for (int p = 0; p < 2; p++) {
    const int qb = p ? (15 - pr) : pr;
    const int nsteps = 2 * qb + 2;          // 32-row KV tiles in [0, (qb+1)*64)
    const int qr0 = qb * 64 + w * 16;
    const int qg = qr0 + qloc;
    const int qmax = qr0 + 15;

    short8 qf[2];
    qf[0] = *(const short8*)&Qh[hb + qg * 64 + g * 8];
    qf[1] = *(const short8*)&Qh[hb + qg * 64 + 32 + g * 8];

    float m_run = -INFINITY, l_lane = 0.f;  // l kept per-lane; reduced at epilogue
    f32x4 o[4] = {};

    // preload tile 0 into regs
    short8 krg = *(const short8*)&Kh[hb + kRow * 64 + kColB];
    short8 vrg = *(const short8*)&Vt[hb + vRow * 1024 + vColB];
    int buf = 0;

    for (int s = 0; s < nsteps; s++) {
      const int kv0 = s * 32;
      *(short8*)&Ks[buf][kRow * 72 + kColB] = krg;
      *(short8*)&Vs[buf][vRow * 40 + vColB] = vrg;
      __syncthreads();
      if (s + 1 < nsteps) {  // issue next tile's loads; latency hides under compute
        const int kn = kv0 + 32;
        krg = *(const short8*)&Kh[hb + (kn + kRow) * 64 + kColB];
        vrg = *(const short8*)&Vt[hb + vRow * 1024 + kn + vColB];
      }
      if (kv0 <= qmax) {  // wave-uniform: skip fully-masked tiles
        f32x4 s2[2] = {};
#pragma unroll
        for (int c = 0; c < 2; c++) {
          short8 a0 = *(const short8*)&Ks[buf][qloc * 72 + c * 32 + g * 8];
          short8 a1 = *(const short8*)&Ks[buf][(16 + qloc) * 72 + c * 32 + g * 8];
          s2[0] = __builtin_amdgcn_mfma_f32_16x16x32_bf16(a0, qf[c], s2[0], 0, 0, 0);
          s2[1] = __builtin_amdgcn_mfma_f32_16x16x32_bf16(a1, qf[c], s2[1], 0, 0, 0);
        }
        // lane holds S[q=qg][k = kv0 + kt*16 + g*4 + r] (exp2-domain after SCL)
        float pv[2][4];
        float pm = -INFINITY;
        if (kv0 + 31 <= qr0) {  // wave-uniform fast path: fully below diagonal
#pragma unroll
          for (int kt = 0; kt < 2; kt++)
#pragma unroll
            for (int r = 0; r < 4; r++) {
              float sv = s2[kt][r] * SCL;
              pv[kt][r] = sv;
              pm = fmaxf(pm, sv);
            }
        } else {
#pragma unroll
          for (int kt = 0; kt < 2; kt++)
#pragma unroll
            for (int r = 0; r < 4; r++) {
              const int kg = kv0 + kt * 16 + g * 4 + r;
              float sv = s2[kt][r] * SCL;
              sv = (kg <= qg) ? sv : -INFINITY;
              pv[kt][r] = sv;
              pm = fmaxf(pm, sv);
            }
        }
        pm = fmaxf(pm, __shfl_xor(pm, 16));
        pm = fmaxf(pm, __shfl_xor(pm, 32));
        if (__all(pm <= m_run + 11.5f)) {
          // defer-max: keep m_run, skip corr-exp and o-rescale (P <= 2^11.5)
          float ls = 0.f;
#pragma unroll
          for (int kt = 0; kt < 2; kt++)
#pragma unroll
            for (int r = 0; r < 4; r++) {
              float pp = exp2f(pv[kt][r] - m_run);
              pv[kt][r] = pp;
              ls += pp;
            }
          l_lane += ls;  // per-lane partial; no shfl here
        } else {
          const float mnew = fmaxf(m_run, pm);
          const float corr = exp2f(m_run - mnew);  // row-uniform
          float ls = 0.f;
#pragma unroll
          for (int kt = 0; kt < 2; kt++)
#pragma unroll
            for (int r = 0; r < 4; r++) {
              float pp = exp2f(pv[kt][r] - mnew);
              pv[kt][r] = pp;
              ls += pp;
            }
          l_lane = l_lane * corr + ls;
          m_run = mnew;
#pragma unroll
          for (int dt = 0; dt < 4; dt++) o[dt] *= corr;
        }
        // repack P (bf16) through per-wave LDS into MFMA B-operand layout
        unsigned int* pp_ = &Ps[w][qloc * 36];
#pragma unroll
        for (int kt = 0; kt < 2; kt++) {
          pp_[kt * 8 + g * 2] = pack2bf(pv[kt][0], pv[kt][1]);
          pp_[kt * 8 + g * 2 + 1] = pack2bf(pv[kt][2], pv[kt][3]);
        }
        __asm__ volatile("" ::: "memory");
        short8 pf = *(const short8*)((const short*)&Ps[w][0] + qloc * 72 + g * 8);
#pragma unroll
        for (int dt = 0; dt < 4; dt++) {
          short8 vf = *(const short8*)&Vs[buf][(dt * 16 + qloc) * 40 + g * 8];
          o[dt] = __builtin_amdgcn_mfma_f32_16x16x32_bf16(vf, pf, o[dt], 0, 0, 0);
        }
      }
      __syncthreads();
      buf ^= 1;
    }

    float l_tot = l_lane + __shfl_xor(l_lane, 16);
    l_tot += __shfl_xor(l_tot, 32);
    const float inv = 1.f / l_tot;
    const int outRow = nIdx * 1024 + qr0 + qloc;
    short* op = Obuf + (size_t)outRow * 768 + hIdx * 64;
#pragma unroll
    for (int dt = 0; dt < 4; dt++) {
      short4v ov;
#pragma unroll
      for (int r = 0; r < 4; r++) ov[r] = (short)f2bf(o[dt][r] * inv);
      *(short4v*)(op + dt * 16 + g * 4) = ov;
    }
  }
}

// ---------------- launch ----------------
extern "C" void kernel_launch(void* const* d_in, const int* in_sizes, int n_in,
                              void* d_out, int out_size, void* d_ws, size_t ws_size,
                              hipStream_t stream) {
  (void)in_sizes; (void)n_in; (void)out_size; (void)ws_size;
  const float* x  = (const float*)d_in[0];
  const float* Wq = (const float*)d_in[1];
  const float* Wk = (const float*)d_in[2];
  const float* Wv = (const float*)d_in[3];
  const float* Wo = (const float*)d_in[4];
  const float* bo = (const float*)d_in[5];

  char* ws = (char*)d_ws;
  short* xb  = (short*)(ws);                              // 8192x768 bf16
  short* wqb = (short*)(ws + 12582912);                   // wq,wk,wv,wo contiguous
  short* wob = (short*)(ws + 12582912 + 3 * 1179648);
  short* Qh  = (short*)(ws + 17301504);                   // [96][1024][64] bf16
  short* Kh  = (short*)(ws + 17301504 + 12582912);
  short* Vt  = (short*)(ws + 17301504 + 2 * 12582912);    // [96][64][1024] bf16
  short* Ob  = (short*)(ws + 17301504 + 3 * 12582912);    // [8192][768] bf16

  cvt_bf16<<<6144, 256, 0, stream>>>(x, (unsigned short*)xb, 1572864);
  cvt_w4<<<2304, 256, 0, stream>>>(Wq, Wk, Wv, Wo, (unsigned short*)wqb);

  gemm_qkv<<<dim3(64, 18), 256, 0, stream>>>(xb, wqb, (unsigned short*)Qh,
                                             (unsigned short*)Vt);

  attn_fwd<<<768, 256, 0, stream>>>(Qh, Kh, Vt, Ob);

  gemm_out<<<dim3(64, 6), 256, 0, stream>>>(Ob, wob, (float*)d_out, bo);
}